// Round 1
// baseline (1826.636 us; speedup 1.0000x reference)
//
#include <hip/hip_runtime.h>
#include <math.h>

// Problem constants (from reference): B=2, S=2048, D=1024, H=16, DH=64
#define BATCH 2
#define SEQ 2048
#define DMODEL 1024
#define NHEAD 16
#define DHEAD 64
#define QKV_COLS (3 * DMODEL)          // 3072
#define EPS 1e-8f

// ---------------------------------------------------------------------------
// Kernel 1/4: f32 SGEMM, C[M,N] = A[M,K] @ B[K,N], all row-major.
// 128x128 block tile, BK=16, 256 threads, 8x8 microtile per thread.
// M,N multiples of 128; K multiple of 16 (true for both GEMMs here).
// ---------------------------------------------------------------------------
#define BM 128
#define BN 128
#define BK 16

__global__ __launch_bounds__(256) void sgemm_kernel(
    const float* __restrict__ A, const float* __restrict__ B,
    float* __restrict__ C, int M, int N, int K) {
  __shared__ float As[BK][BM + 4];   // stored transposed: As[k][m]; +4 keeps float4 alignment
  __shared__ float Bs[BK][BN + 4];

  const int t = threadIdx.x;
  const int n0 = blockIdx.x * BN;
  const int m0 = blockIdx.y * BM;
  const int tx = t & 15;
  const int ty = t >> 4;

  float acc[8][8] = {};

  for (int k0 = 0; k0 < K; k0 += BK) {
    // Load A tile (128 rows x 16 cols), store transposed into As[k][m].
#pragma unroll
    for (int p = 0; p < 2; ++p) {
      const int row = (t >> 2) + p * 64;      // 0..127
      const int col = (t & 3) * 4;            // 0,4,8,12
      const float4 a = *(const float4*)(A + (size_t)(m0 + row) * K + k0 + col);
      As[col + 0][row] = a.x;
      As[col + 1][row] = a.y;
      As[col + 2][row] = a.z;
      As[col + 3][row] = a.w;
    }
    // Load B tile (16 rows x 128 cols).
#pragma unroll
    for (int p = 0; p < 2; ++p) {
      const int row = (t >> 5) + p * 8;       // 0..15
      const int col = (t & 31) * 4;           // 0..124
      *(float4*)(&Bs[row][col]) =
          *(const float4*)(B + (size_t)(k0 + row) * N + n0 + col);
    }
    __syncthreads();

#pragma unroll
    for (int k = 0; k < BK; ++k) {
      float a[8], b[8];
      *(float4*)(a)     = *(const float4*)(&As[k][ty * 8]);
      *(float4*)(a + 4) = *(const float4*)(&As[k][ty * 8 + 4]);
      *(float4*)(b)     = *(const float4*)(&Bs[k][tx * 8]);
      *(float4*)(b + 4) = *(const float4*)(&Bs[k][tx * 8 + 4]);
#pragma unroll
      for (int i = 0; i < 8; ++i)
#pragma unroll
        for (int j = 0; j < 8; ++j)
          acc[i][j] += a[i] * b[j];
    }
    __syncthreads();
  }

#pragma unroll
  for (int i = 0; i < 8; ++i) {
    float* c = C + (size_t)(m0 + ty * 8 + i) * N + n0 + tx * 8;
    *(float4*)(c)     = make_float4(acc[i][0], acc[i][1], acc[i][2], acc[i][3]);
    *(float4*)(c + 4) = make_float4(acc[i][4], acc[i][5], acc[i][6], acc[i][7]);
  }
}

// ---------------------------------------------------------------------------
// Kernel 2: L2-normalize Q and K head-rows in-place inside qkv [B,S,3D].
// One wave per (b, s, h, which∈{q,k}) row of DHEAD=64 elements.
// Folds tau[h] * (1/sqrt(DH)) into Q.
// ---------------------------------------------------------------------------
__global__ __launch_bounds__(256) void qknorm_kernel(
    float* __restrict__ qkv, const float* __restrict__ tau) {
  const int lane = threadIdx.x & 63;
  const int idx = blockIdx.x * 4 + (threadIdx.x >> 6);  // wave index, 0..131071
  const int which = idx & 1;            // 0 = q, 1 = k
  const int h = (idx >> 1) & 15;
  const int s = (idx >> 5) & 2047;
  const int b = idx >> 16;

  float* p = qkv + ((size_t)(b * SEQ + s)) * QKV_COLS + which * DMODEL + h * DHEAD + lane;
  const float v = *p;
  float ss = v * v;
#pragma unroll
  for (int off = 32; off > 0; off >>= 1) ss += __shfl_xor(ss, off, 64);
  const float norm = sqrtf(ss);
  float scale = 1.0f / (norm + EPS);
  if (which == 0) scale *= tau[h] * 0.125f;  // tau / sqrt(DHEAD)
  *p = v * scale;
}

// ---------------------------------------------------------------------------
// Kernel 3: causal flash attention, f32.
// grid = (B*H, S/64); block = 128 threads = 2 waves.
// Each lane owns one query row (q, o in registers). The two waves split key
// tiles by parity and merge their online-softmax state through LDS.
// K/V row addresses are block-uniform -> scalar (s_load) broadcasts.
// Writes attn output in [B,S,D] layout (transpose folded into addressing).
// ---------------------------------------------------------------------------
__global__ __launch_bounds__(128) void attn_kernel(
    const float* __restrict__ qkv, float* __restrict__ attn) {
  const int bh = blockIdx.x;
  const int b = bh >> 4;
  const int h = bh & 15;
  const int qtile = blockIdx.y;
  const int lane = threadIdx.x & 63;
  const int w = threadIdx.x >> 6;
  const int qi = qtile * 64 + lane;

  const float* __restrict__ base = qkv + (size_t)b * SEQ * QKV_COLS;
  const float4* qrow = (const float4*)(base + (size_t)qi * QKV_COLS + h * DHEAD);

  float4 q[16];
#pragma unroll
  for (int i = 0; i < 16; ++i) q[i] = qrow[i];

  float m = -1e30f, l = 0.0f;
  float4 o[16];
#pragma unroll
  for (int i = 0; i < 16; ++i) o[i] = make_float4(0.f, 0.f, 0.f, 0.f);

  const float* kb = base + DMODEL + h * DHEAD;       // K head-row base
  const float* vb = base + 2 * DMODEL + h * DHEAD;   // V head-row base

  for (int kt = w; kt <= qtile; kt += 2) {
    const int keybase = kt * 64;
#pragma unroll 2
    for (int j = 0; j < 64; ++j) {
      const int key = keybase + j;
      const float4* krow = (const float4*)(kb + (size_t)key * QKV_COLS);
      float4 a4 = make_float4(0.f, 0.f, 0.f, 0.f);
#pragma unroll
      for (int i = 0; i < 16; ++i) {
        const float4 kv = krow[i];
        a4.x += q[i].x * kv.x;
        a4.y += q[i].y * kv.y;
        a4.z += q[i].z * kv.z;
        a4.w += q[i].w * kv.w;
      }
      const float s = (a4.x + a4.y) + (a4.z + a4.w);
      const bool valid = (key <= qi);
      const float sv = valid ? s : -1e30f;
      const float mn = fmaxf(m, sv);
      const float alpha = __expf(m - mn);
      const float p = valid ? __expf(sv - mn) : 0.0f;
      l = l * alpha + p;
      const float4* vrow = (const float4*)(vb + (size_t)key * QKV_COLS);
#pragma unroll
      for (int i = 0; i < 16; ++i) {
        const float4 vv = vrow[i];
        o[i].x = o[i].x * alpha + p * vv.x;
        o[i].y = o[i].y * alpha + p * vv.y;
        o[i].z = o[i].z * alpha + p * vv.z;
        o[i].w = o[i].w * alpha + p * vv.w;
      }
      m = mn;
    }
  }

  // Merge wave 1's partial state into wave 0 via LDS, then write output.
  __shared__ float sm[64];
  __shared__ float sl[64];
  __shared__ float so[64][68];  // [query][d], +4 pad keeps float4 alignment

  if (w == 1) {
    sm[lane] = m;
    sl[lane] = l;
#pragma unroll
    for (int i = 0; i < 16; ++i) *(float4*)(&so[lane][i * 4]) = o[i];
  }
  __syncthreads();
  if (w == 0) {
    const float m1 = sm[lane];
    const float l1 = sl[lane];
    const float mn = fmaxf(m, m1);
    const float a0 = __expf(m - mn);
    const float a1 = __expf(m1 - mn);
    const float lt = l * a0 + l1 * a1;   // > 0: wave 0 always sees the diagonal key
    const float inv = 1.0f / lt;
    float* orow = attn + (size_t)(b * SEQ + qi) * DMODEL + h * DHEAD;
#pragma unroll
    for (int i = 0; i < 16; ++i) {
      const float4 o1 = *(const float4*)(&so[lane][i * 4]);
      float4 r;
      r.x = (o[i].x * a0 + o1.x * a1) * inv;
      r.y = (o[i].y * a0 + o1.y * a1) * inv;
      r.z = (o[i].z * a0 + o1.z * a1) * inv;
      r.w = (o[i].w * a0 + o1.w * a1) * inv;
      *(float4*)(orow + i * 4) = r;
    }
  }
}

// ---------------------------------------------------------------------------
// Launch
// ---------------------------------------------------------------------------
extern "C" void kernel_launch(void* const* d_in, const int* in_sizes, int n_in,
                              void* d_out, int out_size, void* d_ws, size_t ws_size,
                              hipStream_t stream) {
  const float* x    = (const float*)d_in[0];
  // d_in[1] is the mask: fixed causal tril -> handled analytically, never read.
  const float* Wqkv = (const float*)d_in[2];
  const float* Wo   = (const float*)d_in[3];
  const float* tau  = (const float*)d_in[4];
  float* out = (float*)d_out;

  float* qkv  = (float*)d_ws;                       // [B,S,3D] = 12,582,912 f32 (50.3 MB)
  float* attn = qkv + (size_t)BATCH * SEQ * QKV_COLS; // [B,S,D] = 4,194,304 f32 (16.8 MB)

  // 1) qkv = x @ Wqkv            (M=4096, N=3072, K=1024)
  sgemm_kernel<<<dim3(QKV_COLS / BN, (BATCH * SEQ) / BM), 256, 0, stream>>>(
      x, Wqkv, qkv, BATCH * SEQ, QKV_COLS, DMODEL);

  // 2) L2-normalize q,k per head; fold tau/sqrt(DH) into q.
  qknorm_kernel<<<(BATCH * SEQ * NHEAD * 2) / 4, 256, 0, stream>>>(qkv, tau);

  // 3) causal flash attention -> attn [B,S,D]
  attn_kernel<<<dim3(BATCH * NHEAD, SEQ / 64), 128, 0, stream>>>(qkv, attn);

  // 4) out = attn @ Wo           (M=4096, N=1024, K=1024)
  sgemm_kernel<<<dim3(DMODEL / BN, (BATCH * SEQ) / BM), 256, 0, stream>>>(
      attn, Wo, out, BATCH * SEQ, DMODEL, DMODEL);
}

// Round 2
// 670.847 us; speedup vs baseline: 2.7229x; 2.7229x over previous
//
#include <hip/hip_runtime.h>
#include <math.h>

// Problem constants (from reference): B=2, S=2048, D=1024, H=16, DH=64
#define BATCH 2
#define SEQ 2048
#define DMODEL 1024
#define NHEAD 16
#define DHEAD 64
#define QKV_COLS (3 * DMODEL)          // 3072
#define EPS 1e-8f

typedef short bf16x8 __attribute__((ext_vector_type(8)));   // 8 bf16 (4 VGPRs)
typedef float f32x4 __attribute__((ext_vector_type(4)));    // 4 fp32 acc

// round-to-nearest-even float -> bf16 (as raw ushort)
static __device__ __forceinline__ unsigned short f2bf(float x) {
  unsigned u = __float_as_uint(x);
  u += 0x7fffu + ((u >> 16) & 1u);
  return (unsigned short)(u >> 16);
}

// ---------------------------------------------------------------------------
// Kernel 1/4: f32 SGEMM, C[M,N] = A[M,K] @ B[K,N], all row-major.
// 128x128 block tile, BK=16, 256 threads, 8x8 microtile per thread.
// ---------------------------------------------------------------------------
#define BM 128
#define BN 128
#define BK 16

__global__ __launch_bounds__(256) void sgemm_kernel(
    const float* __restrict__ A, const float* __restrict__ B,
    float* __restrict__ C, int M, int N, int K) {
  __shared__ float As[BK][BM + 4];
  __shared__ float Bs[BK][BN + 4];

  const int t = threadIdx.x;
  const int n0 = blockIdx.x * BN;
  const int m0 = blockIdx.y * BM;
  const int tx = t & 15;
  const int ty = t >> 4;

  float acc[8][8] = {};

  for (int k0 = 0; k0 < K; k0 += BK) {
#pragma unroll
    for (int p = 0; p < 2; ++p) {
      const int row = (t >> 2) + p * 64;
      const int col = (t & 3) * 4;
      const float4 a = *(const float4*)(A + (size_t)(m0 + row) * K + k0 + col);
      As[col + 0][row] = a.x;
      As[col + 1][row] = a.y;
      As[col + 2][row] = a.z;
      As[col + 3][row] = a.w;
    }
#pragma unroll
    for (int p = 0; p < 2; ++p) {
      const int row = (t >> 5) + p * 8;
      const int col = (t & 31) * 4;
      *(float4*)(&Bs[row][col]) =
          *(const float4*)(B + (size_t)(k0 + row) * N + n0 + col);
    }
    __syncthreads();

#pragma unroll
    for (int k = 0; k < BK; ++k) {
      float a[8], b[8];
      *(float4*)(a)     = *(const float4*)(&As[k][ty * 8]);
      *(float4*)(a + 4) = *(const float4*)(&As[k][ty * 8 + 4]);
      *(float4*)(b)     = *(const float4*)(&Bs[k][tx * 8]);
      *(float4*)(b + 4) = *(const float4*)(&Bs[k][tx * 8 + 4]);
#pragma unroll
      for (int i = 0; i < 8; ++i)
#pragma unroll
        for (int j = 0; j < 8; ++j)
          acc[i][j] += a[i] * b[j];
    }
    __syncthreads();
  }

#pragma unroll
  for (int i = 0; i < 8; ++i) {
    float* c = C + (size_t)(m0 + ty * 8 + i) * N + n0 + tx * 8;
    *(float4*)(c)     = make_float4(acc[i][0], acc[i][1], acc[i][2], acc[i][3]);
    *(float4*)(c + 4) = make_float4(acc[i][4], acc[i][5], acc[i][6], acc[i][7]);
  }
}

// ---------------------------------------------------------------------------
// Kernel 2: read qkv f32 [B,S,3D]; L2-normalize q,k per head (fold tau/sqrt(DH)
// into q); emit bf16 Q/K/V in head-major [B,H,S,DH] for the MFMA attention.
// grid = (B*S, 12); block = 256 (4 waves). wave -> (which in {q,k,v}, h).
// ---------------------------------------------------------------------------
__global__ __launch_bounds__(256) void qknorm_kernel(
    const float* __restrict__ qkv, const float* __restrict__ tau,
    unsigned short* __restrict__ Qh, unsigned short* __restrict__ Kh,
    unsigned short* __restrict__ Vh) {
  const int lane = threadIdx.x & 63;
  const int widx = blockIdx.y * 4 + (threadIdx.x >> 6);  // 0..47
  const int which = widx >> 4;                           // 0=q, 1=k, 2=v
  const int h = widx & 15;
  const int bs = blockIdx.x;                             // 0..B*S-1
  const int b = bs >> 11;
  const int s = bs & 2047;

  const float v = qkv[(size_t)bs * QKV_COLS + which * DMODEL + h * DHEAD + lane];
  float out;
  if (which == 2) {
    out = v;
  } else {
    float ss = v * v;
#pragma unroll
    for (int off = 32; off > 0; off >>= 1) ss += __shfl_xor(ss, off, 64);
    float scale = 1.0f / (sqrtf(ss) + EPS);
    if (which == 0) scale *= tau[h] * 0.125f;  // tau / sqrt(DHEAD)
    out = v * scale;
  }
  unsigned short* dst = (which == 0) ? Qh : (which == 1) ? Kh : Vh;
  dst[((size_t)(b * NHEAD + h) * SEQ + s) * DHEAD + lane] = f2bf(out);
}

// ---------------------------------------------------------------------------
// Kernel 3: causal flash attention with bf16 MFMA (16x16x32).
// grid = (B*H, S/64); block = 256 = 4 waves; wave w owns queries
// qblk*64 + w*16 .. +15. Per 32-key step: 4 QK^T MFMAs, C-layout online
// softmax, P->LDS->A-layout round trip, V staged transposed in LDS, 4 PV
// MFMAs. Verified layouts (m89/m120): C/D row=(lane>>4)*4+reg, col=lane&15;
// A operand: m=lane&15, k=(lane>>4)*8+j.
// ---------------------------------------------------------------------------
#define VT_STRIDE 40   // 32 keys + 8 pad shorts: 80 B rows, 16B-aligned frags
#define PL_STRIDE 40

__global__ __launch_bounds__(256) void attn_kernel(
    const unsigned short* __restrict__ Qh, const unsigned short* __restrict__ Kh,
    const unsigned short* __restrict__ Vh, float* __restrict__ attn) {
  __shared__ unsigned short Vt[DHEAD * VT_STRIDE];     // V^T tile: [d'][key]
  __shared__ unsigned short Pl[4][16 * PL_STRIDE];     // per-wave P: [q][key]

  const int bh = blockIdx.x;
  const int b = bh >> 4;
  const int h = bh & 15;
  const int qblk = blockIdx.y;
  const int t = threadIdx.x;
  const int w = t >> 6;
  const int lane = t & 63;
  const int quad = lane >> 4;
  const int lr = lane & 15;
  const int q0 = qblk * 64 + w * 16;

  const unsigned short* Qp = Qh + (size_t)bh * SEQ * DHEAD;
  const unsigned short* Kp = Kh + (size_t)bh * SEQ * DHEAD;
  const unsigned short* Vp = Vh + (size_t)bh * SEQ * DHEAD;

  // Q fragments (row = q0+lr, k-slices d=0..31 and 32..63), kept in registers.
  const bf16x8 aq0 = *(const bf16x8*)(Qp + (size_t)(q0 + lr) * DHEAD + quad * 8);
  const bf16x8 aq1 = *(const bf16x8*)(Qp + (size_t)(q0 + lr) * DHEAD + 32 + quad * 8);

  const f32x4 zero4 = {0.f, 0.f, 0.f, 0.f};
  f32x4 o[4];
  o[0] = o[1] = o[2] = o[3] = zero4;
  float m_[4] = {-1e30f, -1e30f, -1e30f, -1e30f};
  float l_[4] = {0.f, 0.f, 0.f, 0.f};

  const int kend = (qblk + 1) * 64;
  for (int k0 = 0; k0 < kend; k0 += 32) {
    // --- stage V^T tile (32 keys x 64 d) cooperatively, 256 threads ---
    const int kk = t >> 3;            // 0..31 key within tile
    const int d0 = (t & 7) * 8;       // 0..56
    const bf16x8 vv = *(const bf16x8*)(Vp + (size_t)(k0 + kk) * DHEAD + d0);
    __syncthreads();                  // previous step's Vt reads complete
#pragma unroll
    for (int j = 0; j < 8; ++j) Vt[(d0 + j) * VT_STRIDE + kk] = ((unsigned short)vv[j]);
    __syncthreads();                  // Vt ready

    // --- QK^T: two 16-key tiles, K-dim = DH = 64 (2 MFMAs each) ---
    f32x4 c[2];
#pragma unroll
    for (int kt = 0; kt < 2; ++kt) {
      const unsigned short* kr = Kp + (size_t)(k0 + kt * 16 + lr) * DHEAD;
      const bf16x8 bk0 = *(const bf16x8*)(kr + quad * 8);
      const bf16x8 bk1 = *(const bf16x8*)(kr + 32 + quad * 8);
      f32x4 cc = __builtin_amdgcn_mfma_f32_16x16x32_bf16(aq0, bk0, zero4, 0, 0, 0);
      cc = __builtin_amdgcn_mfma_f32_16x16x32_bf16(aq1, bk1, cc, 0, 0, 0);
      c[kt] = cc;
    }

    // --- causal mask + online softmax on C layout ---
    const int key0 = k0 + lr, key1 = k0 + 16 + lr;
    float mn[4], al[4];
#pragma unroll
    for (int r = 0; r < 4; ++r) {
      const int qrow = q0 + quad * 4 + r;
      const float s0 = (key0 <= qrow) ? c[0][r] : -1e30f;
      const float s1 = (key1 <= qrow) ? c[1][r] : -1e30f;
      c[0][r] = s0; c[1][r] = s1;
      float rm = fmaxf(s0, s1);
      rm = fmaxf(rm, __shfl_xor(rm, 1, 16));
      rm = fmaxf(rm, __shfl_xor(rm, 2, 16));
      rm = fmaxf(rm, __shfl_xor(rm, 4, 16));
      rm = fmaxf(rm, __shfl_xor(rm, 8, 16));
      mn[r] = fmaxf(m_[r], rm);
      al[r] = __expf(m_[r] - mn[r]);
      m_[r] = mn[r];
    }
#pragma unroll
    for (int r = 0; r < 4; ++r) {
      const int qrow = q0 + quad * 4 + r;
      const float p0 = (key0 <= qrow) ? __expf(c[0][r] - mn[r]) : 0.f;
      const float p1 = (key1 <= qrow) ? __expf(c[1][r] - mn[r]) : 0.f;
      float rs = p0 + p1;
      rs += __shfl_xor(rs, 1, 16);
      rs += __shfl_xor(rs, 2, 16);
      rs += __shfl_xor(rs, 4, 16);
      rs += __shfl_xor(rs, 8, 16);
      l_[r] = l_[r] * al[r] + rs;
#pragma unroll
      for (int nt = 0; nt < 4; ++nt) o[nt][r] *= al[r];
      // write P (C layout) to per-wave LDS as bf16
      Pl[w][(quad * 4 + r) * PL_STRIDE + lr] = f2bf(p0);
      Pl[w][(quad * 4 + r) * PL_STRIDE + 16 + lr] = f2bf(p1);
    }

    // --- PV: A = P (16x32 from LDS, A layout), B = V^T rows (contig keys) ---
    const bf16x8 pa = *(const bf16x8*)&Pl[w][lr * PL_STRIDE + quad * 8];
#pragma unroll
    for (int nt = 0; nt < 4; ++nt) {
      const bf16x8 vb = *(const bf16x8*)&Vt[(nt * 16 + lr) * VT_STRIDE + quad * 8];
      o[nt] = __builtin_amdgcn_mfma_f32_16x16x32_bf16(pa, vb, o[nt], 0, 0, 0);
    }
  }

  // --- epilogue: normalize, write attn [B,S,D] f32 ---
#pragma unroll
  for (int r = 0; r < 4; ++r) {
    const int qrow = q0 + quad * 4 + r;
    const float inv = 1.0f / l_[r];
    float* ar = attn + ((size_t)(b * SEQ + qrow)) * DMODEL + h * DHEAD;
#pragma unroll
    for (int nt = 0; nt < 4; ++nt) ar[nt * 16 + lr] = o[nt][r] * inv;
  }
}

// ---------------------------------------------------------------------------
// Launch
// ---------------------------------------------------------------------------
extern "C" void kernel_launch(void* const* d_in, const int* in_sizes, int n_in,
                              void* d_out, int out_size, void* d_ws, size_t ws_size,
                              hipStream_t stream) {
  const float* x    = (const float*)d_in[0];
  // d_in[1] is the mask: fixed causal tril -> handled analytically, never read.
  const float* Wqkv = (const float*)d_in[2];
  const float* Wo   = (const float*)d_in[3];
  const float* tau  = (const float*)d_in[4];
  float* out = (float*)d_out;

  // workspace layout (~92.3 MB total):
  float* qkv  = (float*)d_ws;                          // [B,S,3D] f32, 50.3 MB
  float* attn = qkv + (size_t)BATCH * SEQ * QKV_COLS;  // [B,S,D]  f32, 16.8 MB
  unsigned short* Qh = (unsigned short*)(attn + (size_t)BATCH * SEQ * DMODEL);
  unsigned short* Kh = Qh + (size_t)BATCH * NHEAD * SEQ * DHEAD;  // bf16 8.4 MB each
  unsigned short* Vh = Kh + (size_t)BATCH * NHEAD * SEQ * DHEAD;

  // 1) qkv = x @ Wqkv            (M=4096, N=3072, K=1024)
  sgemm_kernel<<<dim3(QKV_COLS / BN, (BATCH * SEQ) / BM), 256, 0, stream>>>(
      x, Wqkv, qkv, BATCH * SEQ, QKV_COLS, DMODEL);

  // 2) qk-norm + bf16 head-major Q/K/V
  qknorm_kernel<<<dim3(BATCH * SEQ, 12), 256, 0, stream>>>(qkv, tau, Qh, Kh, Vh);

  // 3) causal MFMA flash attention -> attn [B,S,D] f32
  attn_kernel<<<dim3(BATCH * NHEAD, SEQ / 64), 256, 0, stream>>>(Qh, Kh, Vh, attn);

  // 4) out = attn @ Wo           (M=4096, N=1024, K=1024)
  sgemm_kernel<<<dim3(DMODEL / BN, (BATCH * SEQ) / BM), 256, 0, stream>>>(
      attn, Wo, out, BATCH * SEQ, DMODEL, DMODEL);
}

// Round 3
// 340.988 us; speedup vs baseline: 5.3569x; 1.9674x over previous
//
#include <hip/hip_runtime.h>
#include <math.h>

// Problem constants (from reference): B=2, S=2048, D=1024, H=16, DH=64
#define BATCH 2
#define SEQ 2048
#define DMODEL 1024
#define NHEAD 16
#define DHEAD 64
#define QKV_COLS (3 * DMODEL)          // 3072
#define EPS 1e-8f

typedef short bf16x8 __attribute__((ext_vector_type(8)));   // 8 bf16 (4 VGPRs)
typedef float f32x4 __attribute__((ext_vector_type(4)));    // 4 fp32 acc

// round-to-nearest-even float -> bf16 (as raw ushort)
static __device__ __forceinline__ unsigned short f2bf(float x) {
  unsigned u = __float_as_uint(x);
  u += 0x7fffu + ((u >> 16) & 1u);
  return (unsigned short)(u >> 16);
}

// async global->LDS, 16 B per lane (global_load_lds_dwordx4).
// LDS dest semantics: wave-uniform base + lane*16 (m104/m108). lptr must be
// the wave-uniform base; gptr is per-lane. CK-style uintptr detour for as(3).
static __device__ __forceinline__ void async_ld16(const unsigned short* g,
                                                  unsigned short* l) {
  __builtin_amdgcn_global_load_lds(
      (const __attribute__((address_space(1))) void*)g,
      (__attribute__((address_space(3))) void*)(unsigned int)(unsigned long long)l,
      16, 0, 0);
}

// ---------------------------------------------------------------------------
// Prep 1: x f32 [M][K] -> bf16 same layout. 4 floats/thread.
// ---------------------------------------------------------------------------
__global__ __launch_bounds__(256) void convert_x_kernel(
    const float* __restrict__ x, unsigned short* __restrict__ xb) {
  const size_t i = ((size_t)blockIdx.x * 256 + threadIdx.x) * 4;
  const float4 a = *(const float4*)(x + i);
  ushort4 r;
  r.x = f2bf(a.x); r.y = f2bf(a.y); r.z = f2bf(a.z); r.w = f2bf(a.w);
  *(ushort4*)(xb + i) = r;
}

// ---------------------------------------------------------------------------
// Prep 2: W f32 [K][N] -> Wt bf16 [N][K] (transposed), 32x32 LDS tiles.
// grid = (N/32, K/32), block = (32,8).
// ---------------------------------------------------------------------------
__global__ __launch_bounds__(256) void transpose_w_kernel(
    const float* __restrict__ W, unsigned short* __restrict__ Wt, int K, int N) {
  __shared__ float tile[32][33];
  const int n0 = blockIdx.x * 32;
  const int k0 = blockIdx.y * 32;
  const int tx = threadIdx.x, ty = threadIdx.y;
#pragma unroll
  for (int i = 0; i < 4; ++i)
    tile[ty + i * 8][tx] = W[(size_t)(k0 + ty + i * 8) * N + n0 + tx];
  __syncthreads();
#pragma unroll
  for (int i = 0; i < 4; ++i)
    Wt[(size_t)(n0 + ty + i * 8) * K + k0 + tx] = f2bf(tile[tx][ty + i * 8]);
}

// ---------------------------------------------------------------------------
// bf16 MFMA GEMM (m97-style): C[M,N] f32 = A[M,K]bf16 @ Bt[N,K]bf16^T.
// 128x128 block tile, BK=32, 256 threads = 4 waves (2x2), each wave a 64x64
// sub-tile = 4x4 MFMAs of 16x16x32. Staging via global_load_lds width=16.
// K % 32 == 0, M,N % 128 == 0, rows 16B-aligned (K even*8).
// ---------------------------------------------------------------------------
__global__ __launch_bounds__(256) void sgemm_bf16_kernel(
    const unsigned short* __restrict__ A, const unsigned short* __restrict__ Bt,
    float* __restrict__ C, int M, int N, int K) {
  __shared__ unsigned short As[128 * 32];   // [m][k] tile, row-major
  __shared__ unsigned short Bs[128 * 32];   // [n][k] tile, row-major

  const int t = threadIdx.x;
  const int w = t >> 6;
  const int lane = t & 63;
  const int quad = lane >> 4;
  const int lr = lane & 15;
  const int wr = w >> 1, wc = w & 1;
  const int m0 = blockIdx.y * 128;
  const int n0 = blockIdx.x * 128;

  // Staging: each wave covers tile rows [w*32, w*32+32) of both As and Bs,
  // as 2 instructions of 16 rows each (1024 B per instr: lane -> row srow+i*16,
  // 16-byte k-segment (lane&3)*8).
  const int srow = w * 32 + (lane >> 2);
  const int scol = (lane & 3) * 8;
  const unsigned short* ga = A + (size_t)(m0 + srow) * K + scol;
  const unsigned short* gb = Bt + (size_t)(n0 + srow) * K + scol;
  unsigned short* la = &As[(w * 32) * 32];
  unsigned short* lb = &Bs[(w * 32) * 32];

  f32x4 acc[4][4];
  const f32x4 zero4 = {0.f, 0.f, 0.f, 0.f};
#pragma unroll
  for (int i = 0; i < 4; ++i)
#pragma unroll
    for (int j = 0; j < 4; ++j) acc[i][j] = zero4;

  for (int k0 = 0; k0 < K; k0 += 32) {
#pragma unroll
    for (int i = 0; i < 2; ++i) {
      async_ld16(ga + (size_t)(i * 16) * K + k0, la + i * 16 * 32);
      async_ld16(gb + (size_t)(i * 16) * K + k0, lb + i * 16 * 32);
    }
    __syncthreads();   // vmcnt(0) drain: tiles visible

    bf16x8 af[4], bf[4];
#pragma unroll
    for (int i = 0; i < 4; ++i)
      af[i] = *(const bf16x8*)&As[(wr * 64 + i * 16 + lr) * 32 + quad * 8];
#pragma unroll
    for (int j = 0; j < 4; ++j)
      bf[j] = *(const bf16x8*)&Bs[(wc * 64 + j * 16 + lr) * 32 + quad * 8];
#pragma unroll
    for (int i = 0; i < 4; ++i)
#pragma unroll
      for (int j = 0; j < 4; ++j)
        acc[i][j] = __builtin_amdgcn_mfma_f32_16x16x32_bf16(af[i], bf[j], acc[i][j], 0, 0, 0);
    __syncthreads();   // all reads done before next overwrite
  }

  // Epilogue: C/D layout row = quad*4+r, col = lr.
#pragma unroll
  for (int i = 0; i < 4; ++i)
#pragma unroll
    for (int r = 0; r < 4; ++r) {
      float* c = C + (size_t)(m0 + wr * 64 + i * 16 + quad * 4 + r) * N + n0 + wc * 64 + lr;
#pragma unroll
      for (int j = 0; j < 4; ++j) c[j * 16] = acc[i][j][r];
    }
}

// ---------------------------------------------------------------------------
// qknorm: read qkv f32 [B,S,3D]; L2-normalize q,k per head (fold tau/sqrt(DH)
// into q); emit bf16 Q/K/V head-major [B,H,S,DH].
// ---------------------------------------------------------------------------
__global__ __launch_bounds__(256) void qknorm_kernel(
    const float* __restrict__ qkv, const float* __restrict__ tau,
    unsigned short* __restrict__ Qh, unsigned short* __restrict__ Kh,
    unsigned short* __restrict__ Vh) {
  const int lane = threadIdx.x & 63;
  const int widx = blockIdx.y * 4 + (threadIdx.x >> 6);  // 0..47
  const int which = widx >> 4;                           // 0=q, 1=k, 2=v
  const int h = widx & 15;
  const int bs = blockIdx.x;
  const int b = bs >> 11;
  const int s = bs & 2047;

  const float v = qkv[(size_t)bs * QKV_COLS + which * DMODEL + h * DHEAD + lane];
  float out;
  if (which == 2) {
    out = v;
  } else {
    float ss = v * v;
#pragma unroll
    for (int off = 32; off > 0; off >>= 1) ss += __shfl_xor(ss, off, 64);
    float scale = 1.0f / (sqrtf(ss) + EPS);
    if (which == 0) scale *= tau[h] * 0.125f;  // tau / sqrt(DHEAD)
    out = v * scale;
  }
  unsigned short* dst = (which == 0) ? Qh : (which == 1) ? Kh : Vh;
  dst[((size_t)(b * NHEAD + h) * SEQ + s) * DHEAD + lane] = f2bf(out);
}

// ---------------------------------------------------------------------------
// Causal flash attention, bf16 MFMA 16x16x32. grid=(B*H, S/64), 4 waves.
// Writes attn bf16 [B,S,D] (A operand of GEMM2).
// ---------------------------------------------------------------------------
#define VT_STRIDE 40
#define PL_STRIDE 40

__global__ __launch_bounds__(256) void attn_kernel(
    const unsigned short* __restrict__ Qh, const unsigned short* __restrict__ Kh,
    const unsigned short* __restrict__ Vh, unsigned short* __restrict__ attnb) {
  __shared__ unsigned short Vt[DHEAD * VT_STRIDE];     // V^T tile: [d'][key]
  __shared__ unsigned short Pl[4][16 * PL_STRIDE];     // per-wave P: [q][key]

  const int bh = blockIdx.x;
  const int b = bh >> 4;
  const int h = bh & 15;
  const int qblk = blockIdx.y;
  const int t = threadIdx.x;
  const int w = t >> 6;
  const int lane = t & 63;
  const int quad = lane >> 4;
  const int lr = lane & 15;
  const int q0 = qblk * 64 + w * 16;

  const unsigned short* Qp = Qh + (size_t)bh * SEQ * DHEAD;
  const unsigned short* Kp = Kh + (size_t)bh * SEQ * DHEAD;
  const unsigned short* Vp = Vh + (size_t)bh * SEQ * DHEAD;

  const bf16x8 aq0 = *(const bf16x8*)(Qp + (size_t)(q0 + lr) * DHEAD + quad * 8);
  const bf16x8 aq1 = *(const bf16x8*)(Qp + (size_t)(q0 + lr) * DHEAD + 32 + quad * 8);

  const f32x4 zero4 = {0.f, 0.f, 0.f, 0.f};
  f32x4 o[4];
  o[0] = o[1] = o[2] = o[3] = zero4;
  float m_[4] = {-1e30f, -1e30f, -1e30f, -1e30f};
  float l_[4] = {0.f, 0.f, 0.f, 0.f};

  const int kend = (qblk + 1) * 64;
  for (int k0 = 0; k0 < kend; k0 += 32) {
    const int kk = t >> 3;
    const int d0 = (t & 7) * 8;
    const bf16x8 vv = *(const bf16x8*)(Vp + (size_t)(k0 + kk) * DHEAD + d0);
    __syncthreads();
#pragma unroll
    for (int j = 0; j < 8; ++j) Vt[(d0 + j) * VT_STRIDE + kk] = ((unsigned short)vv[j]);
    __syncthreads();

    f32x4 c[2];
#pragma unroll
    for (int kt = 0; kt < 2; ++kt) {
      const unsigned short* kr = Kp + (size_t)(k0 + kt * 16 + lr) * DHEAD;
      const bf16x8 bk0 = *(const bf16x8*)(kr + quad * 8);
      const bf16x8 bk1 = *(const bf16x8*)(kr + 32 + quad * 8);
      f32x4 cc = __builtin_amdgcn_mfma_f32_16x16x32_bf16(aq0, bk0, zero4, 0, 0, 0);
      cc = __builtin_amdgcn_mfma_f32_16x16x32_bf16(aq1, bk1, cc, 0, 0, 0);
      c[kt] = cc;
    }

    const int key0 = k0 + lr, key1 = k0 + 16 + lr;
    float mn[4], al[4];
#pragma unroll
    for (int r = 0; r < 4; ++r) {
      const int qrow = q0 + quad * 4 + r;
      const float s0 = (key0 <= qrow) ? c[0][r] : -1e30f;
      const float s1 = (key1 <= qrow) ? c[1][r] : -1e30f;
      c[0][r] = s0; c[1][r] = s1;
      float rm = fmaxf(s0, s1);
      rm = fmaxf(rm, __shfl_xor(rm, 1, 16));
      rm = fmaxf(rm, __shfl_xor(rm, 2, 16));
      rm = fmaxf(rm, __shfl_xor(rm, 4, 16));
      rm = fmaxf(rm, __shfl_xor(rm, 8, 16));
      mn[r] = fmaxf(m_[r], rm);
      al[r] = __expf(m_[r] - mn[r]);
      m_[r] = mn[r];
    }
#pragma unroll
    for (int r = 0; r < 4; ++r) {
      const int qrow = q0 + quad * 4 + r;
      const float p0 = (key0 <= qrow) ? __expf(c[0][r] - mn[r]) : 0.f;
      const float p1 = (key1 <= qrow) ? __expf(c[1][r] - mn[r]) : 0.f;
      float rs = p0 + p1;
      rs += __shfl_xor(rs, 1, 16);
      rs += __shfl_xor(rs, 2, 16);
      rs += __shfl_xor(rs, 4, 16);
      rs += __shfl_xor(rs, 8, 16);
      l_[r] = l_[r] * al[r] + rs;
#pragma unroll
      for (int nt = 0; nt < 4; ++nt) o[nt][r] *= al[r];
      Pl[w][(quad * 4 + r) * PL_STRIDE + lr] = f2bf(p0);
      Pl[w][(quad * 4 + r) * PL_STRIDE + 16 + lr] = f2bf(p1);
    }

    const bf16x8 pa = *(const bf16x8*)&Pl[w][lr * PL_STRIDE + quad * 8];
#pragma unroll
    for (int nt = 0; nt < 4; ++nt) {
      const bf16x8 vb = *(const bf16x8*)&Vt[(nt * 16 + lr) * VT_STRIDE + quad * 8];
      o[nt] = __builtin_amdgcn_mfma_f32_16x16x32_bf16(pa, vb, o[nt], 0, 0, 0);
    }
  }

#pragma unroll
  for (int r = 0; r < 4; ++r) {
    const int qrow = q0 + quad * 4 + r;
    const float inv = 1.0f / l_[r];
    unsigned short* ar = attnb + ((size_t)(b * SEQ + qrow)) * DMODEL + h * DHEAD;
#pragma unroll
    for (int nt = 0; nt < 4; ++nt) ar[nt * 16 + lr] = f2bf(o[nt][r] * inv);
  }
}

// ---------------------------------------------------------------------------
// Launch
// ---------------------------------------------------------------------------
extern "C" void kernel_launch(void* const* d_in, const int* in_sizes, int n_in,
                              void* d_out, int out_size, void* d_ws, size_t ws_size,
                              hipStream_t stream) {
  const float* x    = (const float*)d_in[0];
  // d_in[1]: fixed causal tril mask -> handled analytically, never read.
  const float* Wqkv = (const float*)d_in[2];
  const float* Wo   = (const float*)d_in[3];
  const float* tau  = (const float*)d_in[4];
  float* out = (float*)d_out;

  // workspace layout (92.3 MB total, same footprint as round 2):
  float* qkv = (float*)d_ws;                                    // [B,S,3D] f32, 50.3 MB
  unsigned short* attnb = (unsigned short*)d_ws;                // bf16 [B,S,D], aliases dead qkv
  unsigned short* Qh = (unsigned short*)(qkv + (size_t)BATCH * SEQ * QKV_COLS);
  unsigned short* Kh = Qh + (size_t)BATCH * NHEAD * SEQ * DHEAD;
  unsigned short* Vh = Kh + (size_t)BATCH * NHEAD * SEQ * DHEAD;
  unsigned short* Xb = Vh + (size_t)BATCH * NHEAD * SEQ * DHEAD;      // bf16 [B*S][D]
  unsigned short* Wqkv_t = Xb + (size_t)BATCH * SEQ * DMODEL;         // bf16 [3D][D]
  unsigned short* Wo_t = Wqkv_t + (size_t)DMODEL * QKV_COLS;          // bf16 [D][D]

  const int M = BATCH * SEQ;  // 4096

  // 0) prep: bf16 conversions + weight transposes
  convert_x_kernel<<<(M * DMODEL) / (256 * 4), 256, 0, stream>>>(x, Xb);
  transpose_w_kernel<<<dim3(QKV_COLS / 32, DMODEL / 32), dim3(32, 8), 0, stream>>>(
      Wqkv, Wqkv_t, DMODEL, QKV_COLS);
  transpose_w_kernel<<<dim3(DMODEL / 32, DMODEL / 32), dim3(32, 8), 0, stream>>>(
      Wo, Wo_t, DMODEL, DMODEL);

  // 1) qkv = x @ Wqkv   (M=4096, N=3072, K=1024), f32 out
  sgemm_bf16_kernel<<<dim3(QKV_COLS / 128, M / 128), 256, 0, stream>>>(
      Xb, Wqkv_t, qkv, M, QKV_COLS, DMODEL);

  // 2) qk-norm -> bf16 head-major Q/K/V
  qknorm_kernel<<<dim3(BATCH * SEQ, 12), 256, 0, stream>>>(qkv, tau, Qh, Kh, Vh);

  // 3) causal MFMA flash attention -> attnb bf16 [B,S,D]
  attn_kernel<<<dim3(BATCH * NHEAD, SEQ / 64), 256, 0, stream>>>(Qh, Kh, Vh, attnb);

  // 4) out = attn @ Wo  (M=4096, N=1024, K=1024), f32 out
  sgemm_bf16_kernel<<<dim3(DMODEL / 128, M / 128), 256, 0, stream>>>(
      attnb, Wo_t, out, M, DMODEL, DMODEL);
}